// Round 1
// 521.865 us; speedup vs baseline: 1.0047x; 1.0047x over previous
//
#include <hip/hip_runtime.h>
#include <stdint.h>

// ---- problem constants ----
#define NTOK 32768
#define EMB  1024
#define QKVN 3072   // 3*EMB
#define NH   16
#define HD   64

typedef __bf16 bf16x8 __attribute__((ext_vector_type(8)));
typedef float  floatx4 __attribute__((ext_vector_type(4)));
typedef unsigned int   uintx4   __attribute__((ext_vector_type(4)));
typedef unsigned short ushortx4 __attribute__((ext_vector_type(4)));
typedef unsigned short ushortx8 __attribute__((ext_vector_type(8)));

__device__ __forceinline__ unsigned short f2bf_rne(float f){
    unsigned int x; __builtin_memcpy(&x, &f, 4);
    x += 0x7fffu + ((x >> 16) & 1u);
    return (unsigned short)(x >> 16);
}

__device__ __forceinline__ void async_copy16(void* lds, const void* gsrc){
    __builtin_amdgcn_global_load_lds(
        (const __attribute__((address_space(1))) unsigned int*)gsrc,
        (__attribute__((address_space(3))) unsigned int*)lds,
        16, 0, 0);
}

// ---------------- cast fp32 -> bf16, vectorized x4 ----------------
__global__ __launch_bounds__(256) void cast_f32_bf16(const float* __restrict__ in,
                                                     unsigned short* __restrict__ out,
                                                     int n4){
    int idx = blockIdx.x * 256 + threadIdx.x;
    if (idx < n4){
        floatx4 v = ((const floatx4*)in)[idx];
        ushortx4 o;
        o[0] = f2bf_rne(v[0]); o[1] = f2bf_rne(v[1]);
        o[2] = f2bf_rne(v[2]); o[3] = f2bf_rne(v[3]);
        ((ushortx4*)out)[idx] = o;
    }
}

// =======================================================================
// QKV GEMM, 256x256 tile, BK=64, 8 waves, 4-phase counted-vmcnt pipeline.
// C[m][n] = sum_k A[m][k]*B[n][k] + bias[n], A/B/C bf16 (B given row-major
// as W so it's already B^T-as-[n][k]).
//
// LDS: 2 K-tile buffers, each {A 256x64 bf16 (32KB), B 256x64 (32KB)} = 128KB.
// Layout row-major [row][64] with 16B-chunk XOR swizzle: data for global
// k-chunk (c ^ (row&7)) lives at LDS chunk c. Staging writes linearly
// (global_load_lds) with the inverse-swizzled GLOBAL source address;
// ds_read_b128 applies the same XOR. Involution => reader gets wanted chunk.
//
// Staging halves (read-staggered so overwrite of the in-use buffer is safe):
//   A-half h = rows {h*64..h*64+63} U {128+h*64..128+h*64+63} (per-wave-row)
//   B-half h = rows {qg*64+h*32..+31 : qg=0..3}               (per-wave-col)
// Quadrant walk per tile: (A0B0)(A0B1)(A1B1)(A1B0). Issue map:
//   q0: T_{t+1}.A-H1 -> nxt   q1: T_{t+1}.B-H0 -> nxt
//   q2: T_{t+2}.A-H0 -> cur   q3: T_{t+2}.B-H1 -> cur
// One s_waitcnt vmcnt(4) per tile boundary (2 half-tiles = 4 loads in flight).
// =======================================================================

__device__ __forceinline__ void stage_a_half(unsigned short* At, const unsigned short* A,
                                             int m0, int h, int kt, int tid){
    #pragma unroll
    for (int g = 0; g < 2; g++){
        int row0  = g * 128 + h * 64;
        int rl    = tid >> 3;          // 0..63
        int chunk = tid & 7;
        int row   = row0 + rl;
        int k8    = chunk ^ (row & 7);
        async_copy16((char*)At + row0 * 128 + tid * 16,
                     &A[(size_t)(m0 + row) * EMB + kt + k8 * 8]);
    }
}

__device__ __forceinline__ void stage_b_half(unsigned short* Bt, const unsigned short* B,
                                             int n0, int h, int kt, int tid){
    #pragma unroll
    for (int j = 0; j < 2; j++){
        int qg    = j * 2 + (tid >> 8);
        int row0  = qg * 64 + h * 32;
        int t2    = tid & 255;
        int rl    = t2 >> 3;           // 0..31
        int chunk = tid & 7;
        int row   = row0 + rl;
        int k8    = chunk ^ (row & 7);
        async_copy16((char*)Bt + row0 * 128 + t2 * 16,
                     &B[(size_t)(n0 + row) * EMB + kt + k8 * 8]);
    }
}

#define LDA_HALF(H)                                                                 \
    _Pragma("unroll")                                                               \
    for (int mi = 0; mi < 4; mi++){                                                 \
        int row = wm * 128 + (H) * 64 + mi * 16 + r16;                              \
        _Pragma("unroll")                                                           \
        for (int ks = 0; ks < 2; ks++)                                              \
            a[mi][ks] = *(const bf16x8*)&curA[row * 64 + (((quad + 4*ks) ^ (row & 7)) * 8)]; \
    }

#define LDB_PAIR(NI0)                                                               \
    _Pragma("unroll")                                                               \
    for (int ni = 0; ni < 2; ni++){                                                 \
        int row = wn * 64 + ((NI0) + ni) * 16 + r16;                                \
        _Pragma("unroll")                                                           \
        for (int ks = 0; ks < 2; ks++)                                              \
            b[ni][ks] = *(const bf16x8*)&curB[row * 64 + (((quad + 4*ks) ^ (row & 7)) * 8)]; \
    }

#define MFMA16(MI0, NI0)                                                            \
    _Pragma("unroll")                                                               \
    for (int mi = 0; mi < 4; mi++)                                                  \
        _Pragma("unroll")                                                           \
        for (int ni = 0; ni < 2; ni++)                                              \
            _Pragma("unroll")                                                       \
            for (int ks = 0; ks < 2; ks++)                                          \
                acc[(MI0) + mi][(NI0) + ni] = __builtin_amdgcn_mfma_f32_16x16x32_bf16( \
                    a[mi][ks], b[ni][ks], acc[(MI0) + mi][(NI0) + ni], 0, 0, 0);

__device__ __forceinline__ void ktile_iter(const unsigned short* __restrict__ A,
                                           const unsigned short* __restrict__ B,
                                           unsigned short* curA, unsigned short* curB,
                                           unsigned short* nxtA, unsigned short* nxtB,
                                           int m0, int n0, int kt, int tid,
                                           floatx4 (&acc)[8][4]){
    const int lane = tid & 63;
    const int wave = tid >> 6;
    const int wm = wave >> 2, wn = wave & 3;
    const int r16 = lane & 15, quad = lane >> 4;
    bf16x8 a[4][2], b[2][2];

    // ---- q0: quadrant (A-H0, B-H0) ----
    LDA_HALF(0);
    LDB_PAIR(0);
    stage_a_half(nxtA, A, m0, 1, kt + 64, tid);        // T_{t+1}.A-H1
    __builtin_amdgcn_s_barrier();
    asm volatile("s_waitcnt lgkmcnt(0)" ::: "memory");
    __builtin_amdgcn_s_setprio(1);
    MFMA16(0, 0);
    __builtin_amdgcn_s_setprio(0);
    __builtin_amdgcn_s_barrier();

    // ---- q1: quadrant (A-H0, B-H1) ----
    LDB_PAIR(2);
    stage_b_half(nxtB, B, n0, 0, kt + 64, tid);        // T_{t+1}.B-H0
    __builtin_amdgcn_s_barrier();
    asm volatile("s_waitcnt lgkmcnt(0)" ::: "memory");
    __builtin_amdgcn_s_setprio(1);
    MFMA16(0, 2);
    __builtin_amdgcn_s_setprio(0);
    __builtin_amdgcn_s_barrier();

    // ---- q2: quadrant (A-H1, B-H1) ----
    LDA_HALF(1);
    stage_a_half(curA, A, m0, 0, kt + 128, tid);       // T_{t+2}.A-H0 (cur buf, rows last read q1)
    __builtin_amdgcn_s_barrier();
    asm volatile("s_waitcnt lgkmcnt(0)" ::: "memory");
    __builtin_amdgcn_s_setprio(1);
    MFMA16(4, 2);
    __builtin_amdgcn_s_setprio(0);
    __builtin_amdgcn_s_barrier();

    // ---- q3: quadrant (A-H1, B-H0) ----
    LDB_PAIR(0);
    stage_b_half(curB, B, n0, 1, kt + 128, tid);       // T_{t+2}.B-H1 (cur buf, rows last read q2)
    __builtin_amdgcn_s_barrier();
    asm volatile("s_waitcnt lgkmcnt(0)" ::: "memory");
    __builtin_amdgcn_s_setprio(1);
    MFMA16(4, 0);
    __builtin_amdgcn_s_setprio(0);
    asm volatile("s_waitcnt vmcnt(4)" ::: "memory");   // counted: T_{t+1} landed, 2 halves in flight
    __builtin_amdgcn_s_barrier();
}

__global__ __launch_bounds__(512, 2) void qkv_gemm256(const unsigned short* __restrict__ A,
                                                      const unsigned short* __restrict__ B,
                                                      const float* __restrict__ bias,
                                                      unsigned short* __restrict__ C){
    extern __shared__ __align__(16) unsigned short lds[];
    unsigned short* A0 = lds;             // 32 KB each
    unsigned short* B0 = lds + 16384;
    unsigned short* A1 = lds + 32768;
    unsigned short* B1 = lds + 49152;

    const int tid = threadIdx.x;
    // XCD-aware swizzle: nwg = 1536, 1536 % 8 == 0 -> simple bijective form.
    int bid = blockIdx.x;
    int swz = (bid & 7) * 192 + (bid >> 3);
    int by  = swz / 12;                   // M-tile 0..127 (bx inner -> B-panel L2 reuse)
    int bx  = swz - by * 12;              // N-tile 0..11
    const int m0 = by * 256, n0 = bx * 256;

    floatx4 acc[8][4];
    #pragma unroll
    for (int i = 0; i < 8; i++)
        #pragma unroll
        for (int j = 0; j < 4; j++) acc[i][j] = floatx4{0.f, 0.f, 0.f, 0.f};

    // ---- prologue: T0 fully + T1.{A-H0, B-H1} (the halves the t=0 loop body doesn't issue)
    stage_a_half(A0, A, m0, 0, 0, tid);
    stage_a_half(A0, A, m0, 1, 0, tid);
    stage_b_half(B0, B, n0, 0, 0, tid);
    stage_b_half(B0, B, n0, 1, 0, tid);
    stage_a_half(A1, A, m0, 0, 64, tid);
    stage_b_half(B1, B, n0, 1, 64, tid);
    asm volatile("s_waitcnt vmcnt(4)" ::: "memory");   // T0 landed; T1 partial in flight
    __builtin_amdgcn_s_barrier();

    // ---- main loop: 16 K-tiles (K=1024, BK=64). Tail prefetches overrun K by
    // <=256B into adjacent ws regions and are never consumed.
    #pragma unroll 1
    for (int t = 0; t < 16; t += 2){
        ktile_iter(A, B, A0, B0, A1, B1, m0, n0, t * 64,      tid, acc);
        ktile_iter(A, B, A1, B1, A0, B0, m0, n0, t * 64 + 64, tid, acc);
    }

    // ---- epilogue: C/D layout col = lane&15, row = quad*4 + r (verified) ----
    const int lane = tid & 63;
    const int wave = tid >> 6;
    const int wm = wave >> 2, wn = wave & 3;
    const int r16 = lane & 15, quad = lane >> 4;
    #pragma unroll
    for (int ni = 0; ni < 4; ni++){
        int gcol = n0 + wn * 64 + ni * 16 + r16;
        float bv = bias[gcol];
        #pragma unroll
        for (int mi = 0; mi < 8; mi++){
            #pragma unroll
            for (int r = 0; r < 4; r++){
                int grow = m0 + wm * 128 + mi * 16 + quad * 4 + r;
                C[(size_t)grow * QKVN + gcol] = f2bf_rne(acc[mi][ni][r] + bv);
            }
        }
    }
}

// ---------------- MFMA per-token cross-head attention ----------------
// 4 tokens/block, 256 threads, one wave per token.
// LDS per token (shorts): k[16][72] @0, vT[64][24] @1152, p_bf16[16][24] @2688 -> 3072
// S = Q·K^T via 2x mfma_16x16x32 (K=64); softmax in C-layout (shfl over j);
// P->LDS->A-frag; PV via 4x mfma_16x16x32 with K padded to 32 (quads 2,3 zero).
#define TOKL 3072
#define KOFF 0
#define VOFF 1152
#define POFF 2688

__global__ __launch_bounds__(256) void attn_mfma(const unsigned short* __restrict__ qkv,
                                                 float* __restrict__ out){
    __shared__ unsigned short sm[4 * TOKL];   // 24 KB

    const int tid = threadIdx.x;
    const int n0  = blockIdx.x * 4;

    // ---- stage K (row-padded) and V (transposed) ----
    #pragma unroll
    for (int s = 0; s < 2; s++){
        int c   = tid + s * 256;
        int t   = c >> 7;
        int rem = c & 127;
        int j   = rem >> 3;
        int d8  = (rem & 7) * 8;
        ushortx8 kk = *(const ushortx8*)&qkv[(size_t)(n0 + t) * QKVN + EMB + j * HD + d8];
        *(ushortx8*)&sm[t * TOKL + KOFF + j * 72 + d8] = kk;
        ushortx8 vv = *(const ushortx8*)&qkv[(size_t)(n0 + t) * QKVN + 2 * EMB + j * HD + d8];
        #pragma unroll
        for (int e = 0; e < 8; e++)
            sm[t * TOKL + VOFF + (d8 + e) * 24 + j] = vv[e];
    }
    __syncthreads();

    const int wave = tid >> 6;
    const int lane = tid & 63;
    const int col  = lane & 15;
    const int quad = lane >> 4;
    const int n    = n0 + wave;
    unsigned short* tb = &sm[wave * TOKL];

    // ---- S = Q·K^T ----
    const unsigned short* qrow = qkv + (size_t)n * QKVN + col * HD;
    bf16x8 qf0 = *(const bf16x8*)(qrow + quad * 8);
    bf16x8 qf1 = *(const bf16x8*)(qrow + 32 + quad * 8);
    bf16x8 kf0 = *(const bf16x8*)&tb[KOFF + col * 72 + quad * 8];
    bf16x8 kf1 = *(const bf16x8*)&tb[KOFF + col * 72 + 32 + quad * 8];

    floatx4 sAcc = floatx4{0.f, 0.f, 0.f, 0.f};
    sAcc = __builtin_amdgcn_mfma_f32_16x16x32_bf16(qf0, kf0, sAcc, 0, 0, 0);
    sAcc = __builtin_amdgcn_mfma_f32_16x16x32_bf16(qf1, kf1, sAcc, 0, 0, 0);

    // ---- softmax over j ----
    #pragma unroll
    for (int r = 0; r < 4; r++){
        float sv = sAcc[r] * 0.03125f;
        float m = sv;
        m = fmaxf(m, __shfl_xor(m, 1));
        m = fmaxf(m, __shfl_xor(m, 2));
        m = fmaxf(m, __shfl_xor(m, 4));
        m = fmaxf(m, __shfl_xor(m, 8));
        float p = __expf(sv - m);
        float l = p;
        l += __shfl_xor(l, 1);
        l += __shfl_xor(l, 2);
        l += __shfl_xor(l, 4);
        l += __shfl_xor(l, 8);
        p *= 1.f / l;
        tb[POFF + (quad * 4 + r) * 24 + col] = f2bf_rne(p);
    }

    // ---- P A-frag (K padded to 32; quads 2,3 supply zeros) ----
    bf16x8 pf;
    #pragma unroll
    for (int z = 0; z < 8; z++) pf[z] = (__bf16)0.0f;
    if (quad < 2) pf = *(const bf16x8*)&tb[POFF + col * 24 + quad * 8];

    // ---- O = P·V, 4 d-blocks of 16 ----
    #pragma unroll
    for (int dblk = 0; dblk < 4; dblk++){
        bf16x8 vf;
        #pragma unroll
        for (int z = 0; z < 8; z++) vf[z] = (__bf16)0.0f;
        if (quad < 2) vf = *(const bf16x8*)&tb[VOFF + (dblk * 16 + col) * 24 + quad * 8];
        floatx4 o = __builtin_amdgcn_mfma_f32_16x16x32_bf16(
                        pf, vf, floatx4{0.f, 0.f, 0.f, 0.f}, 0, 0, 0);
        #pragma unroll
        for (int r = 0; r < 4; r++){
            int i = quad * 4 + r;
            out[(size_t)i * (NTOK * HD) + (size_t)n * HD + dblk * 16 + col] = o[r];
        }
    }
}

extern "C" void kernel_launch(void* const* d_in, const int* in_sizes, int n_in,
                              void* d_out, int out_size, void* d_ws, size_t ws_size,
                              hipStream_t stream){
    const float* h = (const float*)d_in[0];   // [32768][1024]
    const float* W = (const float*)d_in[1];   // [3072][1024]
    const float* b = (const float*)d_in[2];   // [3072]
    float* out = (float*)d_out;               // 33554432 fp32

    char* ws = (char*)d_ws;
    unsigned short* h_bf = (unsigned short*)ws;                              // 64 MB
    unsigned short* w_bf = (unsigned short*)(ws + (size_t)64 * 1024 * 1024); // 6 MB
    unsigned short* qkv  = (unsigned short*)(ws + (size_t)72 * 1024 * 1024); // 192 MB bf16

    static bool attr_set = false;
    if (!attr_set){
        hipFuncSetAttribute(reinterpret_cast<const void*>(qkv_gemm256),
                            hipFuncAttributeMaxDynamicSharedMemorySize, 131072);
        attr_set = true;
    }

    cast_f32_bf16<<<(NTOK * EMB / 4 + 255) / 256, 256, 0, stream>>>(h, h_bf, NTOK * EMB / 4);
    cast_f32_bf16<<<(QKVN * EMB / 4 + 255) / 256, 256, 0, stream>>>(W, w_bf, QKVN * EMB / 4);

    qkv_gemm256<<<dim3(1536), 512, 131072, stream>>>(h_bf, w_bf, b, qkv);

    attn_mfma<<<NTOK / 4, 256, 0, stream>>>(qkv, out);
}

// Round 2
// 511.517 us; speedup vs baseline: 1.0250x; 1.0202x over previous
//
#include <hip/hip_runtime.h>
#include <stdint.h>

// ---- problem constants ----
#define NTOK 32768
#define EMB  1024
#define QKVN 3072   // 3*EMB
#define NH   16
#define HD   64

typedef __bf16 bf16x8 __attribute__((ext_vector_type(8)));
typedef float  floatx4 __attribute__((ext_vector_type(4)));
typedef unsigned int   uintx4   __attribute__((ext_vector_type(4)));
typedef unsigned short ushortx4 __attribute__((ext_vector_type(4)));
typedef unsigned short ushortx8 __attribute__((ext_vector_type(8)));

__device__ __forceinline__ unsigned short f2bf_rne(float f){
    unsigned int x; __builtin_memcpy(&x, &f, 4);
    x += 0x7fffu + ((x >> 16) & 1u);
    return (unsigned short)(x >> 16);
}

__device__ __forceinline__ void async_copy16(void* lds, const void* gsrc){
    __builtin_amdgcn_global_load_lds(
        (const __attribute__((address_space(1))) unsigned int*)gsrc,
        (__attribute__((address_space(3))) unsigned int*)lds,
        16, 0, 0);
}

// ---------------- cast fp32 -> bf16, vectorized x4 ----------------
__global__ __launch_bounds__(256) void cast_f32_bf16(const float* __restrict__ in,
                                                     unsigned short* __restrict__ out,
                                                     int n4){
    int idx = blockIdx.x * 256 + threadIdx.x;
    if (idx < n4){
        floatx4 v = ((const floatx4*)in)[idx];
        ushortx4 o;
        o[0] = f2bf_rne(v[0]); o[1] = f2bf_rne(v[1]);
        o[2] = f2bf_rne(v[2]); o[3] = f2bf_rne(v[3]);
        ((ushortx4*)out)[idx] = o;
    }
}

// =======================================================================
// QKV GEMM, 256x256 tile, BK=64, 8 waves, 8-phase READ-AHEAD pipeline.
// Round-1 postmortem: 2-barrier phases serialized read-drain(750cy)+MFMA
// (620cy) -> 36% MfmaUtil. Fix: every ds_read targets the NEXT phase's
// fragments; compiler's fine-grained lgkmcnt then lets reads drain UNDER
// the MFMA cluster. 8 phases/K-tile, 8 MFMA each, 1 barrier/phase.
//
// Walk: p0(A0,B01) p1(A0,B23) p2(A1,B23) p3(A1,B01)
//       p4(A2,B01) p5(A2,B23) p6(A3,B23) p7(A3,B01)
// A quarters alternate reg-sets aX{A0,A2}/aY{A1,A3}; b01/b23 resident/tile.
// Reads: a1@p1, a2@p3, a3@p5, {b23n,a0n}@p7-pre (from NXT), b01n@p7-post.
// Stages (into cur, for tile t+2), each after the barrier that follows the
// region's last read completion:
//   p1: Aq0 + B-h0   p2: B-h1   p3: Aq1   p5: Aq2   p7: Aq3   (8 loads)
// vmcnt(7) at p6-end: 7 younger (this tile's p1..p5) stay in flight; the
// next tile's 8 loads (issued last tile) are forced landed before p7 reads.
// LDS 16B-chunk XOR swizzle as round 1 (bank-conflict 0, keep).
// =======================================================================

__device__ __forceinline__ void stage_a_q(unsigned short* At, const unsigned short* A,
                                          int m0, int q, int kt, int tid){
    int g     = tid >> 8;
    int rl    = (tid & 255) >> 3;
    int chunk = tid & 7;
    int row   = g * 128 + q * 32 + rl;
    int k8    = chunk ^ (row & 7);
    async_copy16((char*)At + row * 128 + chunk * 16,
                 &A[(size_t)(m0 + row) * EMB + kt + k8 * 8]);
}

__device__ __forceinline__ void stage_b_half(unsigned short* Bt, const unsigned short* B,
                                             int n0, int h, int kt, int tid){
    #pragma unroll
    for (int j = 0; j < 2; j++){
        int qg    = j * 2 + (tid >> 8);
        int row0  = qg * 64 + h * 32;
        int t2    = tid & 255;
        int rl    = t2 >> 3;
        int chunk = tid & 7;
        int row   = row0 + rl;
        int k8    = chunk ^ (row & 7);
        async_copy16((char*)Bt + row0 * 128 + t2 * 16,
                     &B[(size_t)(n0 + row) * EMB + kt + k8 * 8]);
    }
}

// ds-read one A quarter (2 m-frags x 2 k-slices) into a reg set
#define LDA_Q(DST, BUF, Q)                                                          \
    _Pragma("unroll")                                                               \
    for (int mi = 0; mi < 2; mi++){                                                 \
        int row = wm * 128 + (Q) * 32 + mi * 16 + r16;                              \
        _Pragma("unroll")                                                           \
        for (int ks = 0; ks < 2; ks++)                                              \
            DST[mi][ks] = *(const bf16x8*)&(BUF)[row * 64 + (((quad + 4*ks) ^ (row & 7)) * 8)]; \
    }

// ds-read one B pair (2 n-frags x 2 k-slices)
#define LDB_P(DST, BUF, P)                                                          \
    _Pragma("unroll")                                                               \
    for (int ni = 0; ni < 2; ni++){                                                 \
        int row = wn * 64 + (P) * 32 + ni * 16 + r16;                               \
        _Pragma("unroll")                                                           \
        for (int ks = 0; ks < 2; ks++)                                              \
            DST[ni][ks] = *(const bf16x8*)&(BUF)[row * 64 + (((quad + 4*ks) ^ (row & 7)) * 8)]; \
    }

#define MFMA8(Q, P, AS, BS)                                                         \
    _Pragma("unroll")                                                               \
    for (int mi = 0; mi < 2; mi++)                                                  \
        _Pragma("unroll")                                                           \
        for (int ni = 0; ni < 2; ni++)                                              \
            _Pragma("unroll")                                                       \
            for (int ks = 0; ks < 2; ks++)                                          \
                acc[(Q)*2 + mi][(P)*2 + ni] = __builtin_amdgcn_mfma_f32_16x16x32_bf16( \
                    AS[mi][ks], BS[ni][ks], acc[(Q)*2 + mi][(P)*2 + ni], 0, 0, 0);

#define SETP1 __builtin_amdgcn_s_setprio(1)
#define SETP0 __builtin_amdgcn_s_setprio(0)
#define BAR   __builtin_amdgcn_s_barrier()

__device__ __forceinline__ void ktile8(const unsigned short* __restrict__ A,
                                       const unsigned short* __restrict__ B,
                                       unsigned short* curA, unsigned short* curB,
                                       unsigned short* nxtA, unsigned short* nxtB,
                                       int m0, int n0, int kt, int tid,
                                       bf16x8 (&aX)[2][2], bf16x8 (&aY)[2][2],
                                       bf16x8 (&b01)[2][2], bf16x8 (&b23)[2][2],
                                       floatx4 (&acc)[8][4]){
    const int lane = tid & 63;
    const int wave = tid >> 6;
    const int wm = wave >> 2, wn = wave & 3;
    const int r16 = lane & 15, quad = lane >> 4;
    const int ks2 = kt + 128;   // staging K-base (tile t+2)

    // p0: MFMA(A0,B01). No reads/stages; barrier lets p1 overwrite read-done regions.
    SETP1; MFMA8(0, 0, aX, b01); SETP0; BAR;

    // p1: read a1 (next phase); stage Aq0 + B-h0 of t+2
    LDA_Q(aY, curA, 1);
    stage_a_q(curA, A, m0, 0, ks2, tid);
    stage_b_half(curB, B, n0, 0, ks2, tid);
    SETP1; MFMA8(0, 1, aX, b23); SETP0; BAR;

    // p2: stage B-h1
    stage_b_half(curB, B, n0, 1, ks2, tid);
    SETP1; MFMA8(1, 1, aY, b23); SETP0; BAR;

    // p3: read a2; stage Aq1
    LDA_Q(aX, curA, 2);
    stage_a_q(curA, A, m0, 1, ks2, tid);
    SETP1; MFMA8(1, 0, aY, b01); SETP0; BAR;

    // p4
    SETP1; MFMA8(2, 0, aX, b01); SETP0; BAR;

    // p5: read a3; stage Aq2
    LDA_Q(aY, curA, 3);
    stage_a_q(curA, A, m0, 2, ks2, tid);
    SETP1; MFMA8(2, 1, aX, b23); SETP0; BAR;

    // p6: counted wait — next tile's 8 loads landed, this tile's 7 in flight
    SETP1; MFMA8(3, 1, aY, b23); SETP0;
    asm volatile("s_waitcnt vmcnt(7)" ::: "memory");
    BAR;

    // p7: pre-read next tile's b23,a0 from NXT; MFMA; post-read b01n (WAR after use);
    //     stage Aq3
    LDB_P(b23, nxtB, 1);
    LDA_Q(aX, nxtA, 0);
    SETP1; MFMA8(3, 0, aY, b01); SETP0;
    LDB_P(b01, nxtB, 0);
    stage_a_q(curA, A, m0, 3, ks2, tid);
    BAR;
}

__global__ __launch_bounds__(512, 2) void qkv_gemm256(const unsigned short* __restrict__ A,
                                                      const unsigned short* __restrict__ B,
                                                      const float* __restrict__ bias,
                                                      unsigned short* __restrict__ C){
    extern __shared__ __align__(16) unsigned short lds[];
    unsigned short* A0 = lds;             // 32 KB each
    unsigned short* B0 = lds + 16384;
    unsigned short* A1 = lds + 32768;
    unsigned short* B1 = lds + 49152;

    const int tid = threadIdx.x;
    // XCD-aware swizzle: nwg = 1536, 1536 % 8 == 0 -> bijective.
    int bid = blockIdx.x;
    int swz = (bid & 7) * 192 + (bid >> 3);
    int by  = swz / 12;
    int bx  = swz - by * 12;
    const int m0 = by * 256, n0 = bx * 256;

    const int lane = tid & 63;
    const int wave = tid >> 6;
    const int wm = wave >> 2, wn = wave & 3;
    const int r16 = lane & 15, quad = lane >> 4;

    floatx4 acc[8][4];
    #pragma unroll
    for (int i = 0; i < 8; i++)
        #pragma unroll
        for (int j = 0; j < 4; j++) acc[i][j] = floatx4{0.f, 0.f, 0.f, 0.f};

    // ---- prologue: stage T0 (8 loads, oldest) then T1 (8 loads) ----
    #pragma unroll
    for (int q = 0; q < 4; q++) stage_a_q(A0, A, m0, q, 0, tid);
    stage_b_half(B0, B, n0, 0, 0, tid);
    stage_b_half(B0, B, n0, 1, 0, tid);
    #pragma unroll
    for (int q = 0; q < 4; q++) stage_a_q(A1, A, m0, q, 64, tid);
    stage_b_half(B1, B, n0, 0, 64, tid);
    stage_b_half(B1, B, n0, 1, 64, tid);
    asm volatile("s_waitcnt vmcnt(8)" ::: "memory");   // T0 landed; T1 in flight
    BAR;

    bf16x8 aX[2][2], aY[2][2], b01[2][2], b23[2][2];
    // pre-reads (mimic t-1.p7): a0, b01, b23 of tile 0
    LDA_Q(aX, A0, 0);
    LDB_P(b01, B0, 0);
    LDB_P(b23, B0, 1);

    // ---- main loop: 16 K-tiles. Tail prefetches overrun K and read adjacent
    // ws regions (allocated); staged garbage is never consumed.
    #pragma unroll 1
    for (int t = 0; t < 16; t += 2){
        ktile8(A, B, A0, B0, A1, B1, m0, n0, t * 64,      tid, aX, aY, b01, b23, acc);
        ktile8(A, B, A1, B1, A0, B0, m0, n0, t * 64 + 64, tid, aX, aY, b01, b23, acc);
    }

    // ---- epilogue: C/D layout col = lane&15, row = quad*4 + r (verified) ----
    #pragma unroll
    for (int ni = 0; ni < 4; ni++){
        int gcol = n0 + wn * 64 + ni * 16 + r16;
        float bv = bias[gcol];
        #pragma unroll
        for (int mi = 0; mi < 8; mi++){
            #pragma unroll
            for (int r = 0; r < 4; r++){
                int grow = m0 + wm * 128 + mi * 16 + quad * 4 + r;
                C[(size_t)grow * QKVN + gcol] = f2bf_rne(acc[mi][ni][r] + bv);
            }
        }
    }
}

// ---------------- MFMA per-token cross-head attention ----------------
#define TOKL 3072
#define KOFF 0
#define VOFF 1152
#define POFF 2688

__global__ __launch_bounds__(256) void attn_mfma(const unsigned short* __restrict__ qkv,
                                                 float* __restrict__ out){
    __shared__ unsigned short sm[4 * TOKL];   // 24 KB

    const int tid = threadIdx.x;
    const int n0  = blockIdx.x * 4;

    // ---- stage K (row-padded) and V (transposed) ----
    #pragma unroll
    for (int s = 0; s < 2; s++){
        int c   = tid + s * 256;
        int t   = c >> 7;
        int rem = c & 127;
        int j   = rem >> 3;
        int d8  = (rem & 7) * 8;
        ushortx8 kk = *(const ushortx8*)&qkv[(size_t)(n0 + t) * QKVN + EMB + j * HD + d8];
        *(ushortx8*)&sm[t * TOKL + KOFF + j * 72 + d8] = kk;
        ushortx8 vv = *(const ushortx8*)&qkv[(size_t)(n0 + t) * QKVN + 2 * EMB + j * HD + d8];
        #pragma unroll
        for (int e = 0; e < 8; e++)
            sm[t * TOKL + VOFF + (d8 + e) * 24 + j] = vv[e];
    }
    __syncthreads();

    const int wave = tid >> 6;
    const int lane = tid & 63;
    const int col  = lane & 15;
    const int quad = lane >> 4;
    const int n    = n0 + wave;
    unsigned short* tb = &sm[wave * TOKL];

    // ---- S = Q·K^T ----
    const unsigned short* qrow = qkv + (size_t)n * QKVN + col * HD;
    bf16x8 qf0 = *(const bf16x8*)(qrow + quad * 8);
    bf16x8 qf1 = *(const bf16x8*)(qrow + 32 + quad * 8);
    bf16x8 kf0 = *(const bf16x8*)&tb[KOFF + col * 72 + quad * 8];
    bf16x8 kf1 = *(const bf16x8*)&tb[KOFF + col * 72 + 32 + quad * 8];

    floatx4 sAcc = floatx4{0.f, 0.f, 0.f, 0.f};
    sAcc = __builtin_amdgcn_mfma_f32_16x16x32_bf16(qf0, kf0, sAcc, 0, 0, 0);
    sAcc = __builtin_amdgcn_mfma_f32_16x16x32_bf16(qf1, kf1, sAcc, 0, 0, 0);

    // ---- softmax over j ----
    #pragma unroll
    for (int r = 0; r < 4; r++){
        float sv = sAcc[r] * 0.03125f;
        float m = sv;
        m = fmaxf(m, __shfl_xor(m, 1));
        m = fmaxf(m, __shfl_xor(m, 2));
        m = fmaxf(m, __shfl_xor(m, 4));
        m = fmaxf(m, __shfl_xor(m, 8));
        float p = __expf(sv - m);
        float l = p;
        l += __shfl_xor(l, 1);
        l += __shfl_xor(l, 2);
        l += __shfl_xor(l, 4);
        l += __shfl_xor(l, 8);
        p *= 1.f / l;
        tb[POFF + (quad * 4 + r) * 24 + col] = f2bf_rne(p);
    }

    // ---- P A-frag (K padded to 32; quads 2,3 supply zeros) ----
    bf16x8 pf;
    #pragma unroll
    for (int z = 0; z < 8; z++) pf[z] = (__bf16)0.0f;
    if (quad < 2) pf = *(const bf16x8*)&tb[POFF + col * 24 + quad * 8];

    // ---- O = P·V, 4 d-blocks of 16 ----
    #pragma unroll
    for (int dblk = 0; dblk < 4; dblk++){
        bf16x8 vf;
        #pragma unroll
        for (int z = 0; z < 8; z++) vf[z] = (__bf16)0.0f;
        if (quad < 2) vf = *(const bf16x8*)&tb[VOFF + (dblk * 16 + col) * 24 + quad * 8];
        floatx4 o = __builtin_amdgcn_mfma_f32_16x16x32_bf16(
                        pf, vf, floatx4{0.f, 0.f, 0.f, 0.f}, 0, 0, 0);
        #pragma unroll
        for (int r = 0; r < 4; r++){
            int i = quad * 4 + r;
            out[(size_t)i * (NTOK * HD) + (size_t)n * HD + dblk * 16 + col] = o[r];
        }
    }
}

extern "C" void kernel_launch(void* const* d_in, const int* in_sizes, int n_in,
                              void* d_out, int out_size, void* d_ws, size_t ws_size,
                              hipStream_t stream){
    const float* h = (const float*)d_in[0];   // [32768][1024]
    const float* W = (const float*)d_in[1];   // [3072][1024]
    const float* b = (const float*)d_in[2];   // [3072]
    float* out = (float*)d_out;               // 33554432 fp32

    char* ws = (char*)d_ws;
    unsigned short* h_bf = (unsigned short*)ws;                              // 64 MB
    unsigned short* w_bf = (unsigned short*)(ws + (size_t)64 * 1024 * 1024); // 6 MB
    unsigned short* qkv  = (unsigned short*)(ws + (size_t)72 * 1024 * 1024); // 192 MB bf16

    static bool attr_set = false;
    if (!attr_set){
        hipFuncSetAttribute(reinterpret_cast<const void*>(qkv_gemm256),
                            hipFuncAttributeMaxDynamicSharedMemorySize, 131072);
        attr_set = true;
    }

    cast_f32_bf16<<<(NTOK * EMB / 4 + 255) / 256, 256, 0, stream>>>(h, h_bf, NTOK * EMB / 4);
    cast_f32_bf16<<<(QKVN * EMB / 4 + 255) / 256, 256, 0, stream>>>(W, w_bf, QKVN * EMB / 4);

    qkv_gemm256<<<dim3(1536), 512, 131072, stream>>>(h_bf, w_bf, b, qkv);

    attn_mfma<<<NTOK / 4, 256, 0, stream>>>(qkv, out);
}